// Round 9
// baseline (40815.585 us; speedup 1.0000x reference)
//
#include <hip/hip_runtime.h>

// R9: serial-f32 mul+add trajectory (the untested v0 class).
// Ladder if fail@8.0: serial-fma -> einsum-SIMD K=32 hybrid -> BLIS kc=512 -> MKL -> structural f64.

#define T_STEPS 128
#define NE 8192
#define NI 2048
#define RDIM 32
#define BTOT 32
#define NTOT 10240
#define NPT 40
#define NW 320
#define DECAYF 0.904837429523468017578125f   // f32(exp(f32(-0.1)))

__global__ __launch_bounds__(256)
void snn_serial_muladd(const float* __restrict__ ext,
                       const float* __restrict__ U_ee, const float* __restrict__ V_ee,
                       const float* __restrict__ U_ei, const float* __restrict__ V_ei,
                       const float* __restrict__ U_ie, const float* __restrict__ V_ie,
                       float* __restrict__ out)
{
    __shared__ float sR1[RDIM], sR2[RDIM], sR3[RDIM];   // (s_e@V_ee), (s_e@V_ei), (s_i@V_ie)
    __shared__ unsigned mw[NW];                          // spike mask words: e 0..255, i 256..319
    __shared__ unsigned short sIe[NE];                   // compacted e-spike indices (16KB)
    __shared__ unsigned short sIi[NI];                   // compacted i-spike indices (4KB)
    __shared__ int sCe, sCi;

    const int tid = threadIdx.x;
    const int b = blockIdx.x;      // one block = one batch trajectory (independent)

    float v[NPT];
    int   acc[NPT];
    #pragma unroll
    for (int j = 0; j < NPT; ++j) { v[j] = 0.f; acc[j] = 0; }
    if (tid < RDIM) { sR1[tid] = 0.f; sR2[tid] = 0.f; sR3[tid] = 0.f; }
    __syncthreads();

    for (int t = 0; t < T_STEPS; ++t) {
        // ---- Phase E: expansion (serial mul+add r-chains) + LIF + spike ----
        #pragma unroll
        for (int j = 0; j < NPT; ++j) {
            const int n = j * 256 + tid;        // j<32: e-neuron n; j>=32: i-neuron n-NE
            float I;
            if (j < 32) {
                const float4* Ua = (const float4*)(U_ee + (size_t)n * RDIM);
                const float4* Ub = (const float4*)(U_ie + (size_t)n * RDIM);
                float t1 = 0.f, t2 = 0.f;
                #pragma unroll
                for (int q = 0; q < 8; ++q) {
                    float4 ua = Ua[q], ub = Ub[q];
                    t1 = __fadd_rn(t1, __fmul_rn(sR1[4*q+0], ua.x));
                    t1 = __fadd_rn(t1, __fmul_rn(sR1[4*q+1], ua.y));
                    t1 = __fadd_rn(t1, __fmul_rn(sR1[4*q+2], ua.z));
                    t1 = __fadd_rn(t1, __fmul_rn(sR1[4*q+3], ua.w));
                    t2 = __fadd_rn(t2, __fmul_rn(sR3[4*q+0], ub.x));
                    t2 = __fadd_rn(t2, __fmul_rn(sR3[4*q+1], ub.y));
                    t2 = __fadd_rn(t2, __fmul_rn(sR3[4*q+2], ub.z));
                    t2 = __fadd_rn(t2, __fmul_rn(sR3[4*q+3], ub.w));
                }
                I = __fadd_rn(__fadd_rn(t1, t2),
                              ext[((size_t)b * T_STEPS + t) * NE + n]);
            } else {
                const float4* Uc = (const float4*)(U_ei + (size_t)(n - NE) * RDIM);
                float t1 = 0.f;
                #pragma unroll
                for (int q = 0; q < 8; ++q) {
                    float4 uc = Uc[q];
                    t1 = __fadd_rn(t1, __fmul_rn(sR2[4*q+0], uc.x));
                    t1 = __fadd_rn(t1, __fmul_rn(sR2[4*q+1], uc.y));
                    t1 = __fadd_rn(t1, __fmul_rn(sR2[4*q+2], uc.z));
                    t1 = __fadd_rn(t1, __fmul_rn(sR2[4*q+3], uc.w));
                }
                I = t1;
            }
            v[j] = __fadd_rn(__fmul_rn(v[j], DECAYF), I);   // v*decay then +I (numpy order)
            const bool sp = (v[j] >= 1.0f);                  // == (v-1.0f >= 0) in f32
            acc[j] += sp ? 1 : 0;
            if (sp) v[j] = 0.f;                              // v*(1-s)
            unsigned long long bal = __ballot(sp);
            const int w = tid >> 6;
            if ((tid & 63) == 0)  mw[j*8 + 2*w]     = (unsigned)bal;
            if ((tid & 63) == 32) mw[j*8 + 2*w + 1] = (unsigned)(bal >> 32);
        }
        if (t == T_STEPS - 1) break;
        __syncthreads();

        // ---- compact spike indices ascending (order = numpy's k order) ----
        if (tid == 0) {
            int c = 0;
            for (int w = 0; w < 256; ++w) {
                unsigned m = mw[w];
                while (m) { int bit = __ffs(m) - 1; m &= m - 1; sIe[c++] = (unsigned short)(w*32 + bit); }
            }
            sCe = c;
        } else if (tid == 64) {
            int c = 0;
            for (int w = 256; w < 320; ++w) {
                unsigned m = mw[w];
                while (m) { int bit = __ffs(m) - 1; m &= m - 1; sIi[c++] = (unsigned short)((w-256)*32 + bit); }
            }
            sCi = c;
        }
        __syncthreads();

        // ---- serial in-order f32 add chains (s@V: products are exact 0/1*V) ----
        if (tid < 96) {
            const int tb = tid >> 5, r = tid & 31;
            const float* V = (tb == 0 ? V_ee : tb == 1 ? V_ei : V_ie) + r;
            const unsigned short* idx = (tb == 2) ? sIi : sIe;
            const int cnt = (tb == 2) ? sCi : sCe;
            float a = 0.f;
            int j2 = 0;
            for (; j2 + 4 <= cnt; j2 += 4) {
                float x1 = V[(size_t)idx[j2]   * RDIM], x2 = V[(size_t)idx[j2+1] * RDIM];
                float x3 = V[(size_t)idx[j2+2] * RDIM], x4 = V[(size_t)idx[j2+3] * RDIM];
                a = __fadd_rn(a, x1); a = __fadd_rn(a, x2);
                a = __fadd_rn(a, x3); a = __fadd_rn(a, x4);
            }
            for (; j2 < cnt; ++j2) a = __fadd_rn(a, V[(size_t)idx[j2] * RDIM]);
            (tb == 0 ? sR1 : tb == 1 ? sR2 : sR3)[r] = a;
        }
        __syncthreads();
    }

    // ---- output spike counts [B][Ne+Ni] ----
    #pragma unroll
    for (int j = 0; j < NPT; ++j) {
        const int n = j * 256 + tid;
        out[(size_t)b * NTOT + n] = (float)acc[j];
    }
}

extern "C" void kernel_launch(void* const* d_in, const int* in_sizes, int n_in,
                              void* d_out, int out_size, void* d_ws, size_t ws_size,
                              hipStream_t stream) {
    (void)in_sizes; (void)n_in; (void)d_ws; (void)ws_size; (void)out_size;
    const float* ext  = (const float*)d_in[0];
    const float* U_ee = (const float*)d_in[1];
    const float* V_ee = (const float*)d_in[2];
    const float* U_ei = (const float*)d_in[3];
    const float* V_ei = (const float*)d_in[4];
    const float* U_ie = (const float*)d_in[5];
    const float* V_ie = (const float*)d_in[6];

    snn_serial_muladd<<<dim3(BTOT), dim3(256), 0, stream>>>(
        ext, U_ee, V_ee, U_ei, V_ei, U_ie, V_ie, (float*)d_out);
}

// Round 12
// 26406.055 us; speedup vs baseline: 1.5457x; 1.5457x over previous
//
#include <hip/hip_runtime.h>

// R12 = R11 with the 256-thread/320-word compaction index bug fixed (R11 left
// pc[256..319] uninitialized -> garbage sCi -> OOB -> SIGABRT). Arithmetic
// identical to R9 (passed, absmax 0): serial mul+add r-chains, (t1+t2)+ext,
// v*decay+I, ascending serial f32 V-chains.

#define T_STEPS 128
#define NE 8192
#define NI 2048
#define NTOT 10240
#define RDIM 32
#define BTOT 32
#define NPT 40
#define NW 320
#define DECAYF 0.904837429523468017578125f   // f32(exp(f32(-0.1)))

__global__ __launch_bounds__(256)
void snn_fast(const float* __restrict__ ext,
              const float* __restrict__ U_ee, const float* __restrict__ V_ee,
              const float* __restrict__ U_ei, const float* __restrict__ V_ei,
              const float* __restrict__ U_ie, const float* __restrict__ V_ie,
              float* __restrict__ out)
{
    __shared__ float sR1[RDIM], sR2[RDIM], sR3[RDIM];
    __shared__ unsigned mw[NW];            // spike masks: e words 0..255, i words 256..319
    __shared__ unsigned pc[NW];            // popcount / prefix scan
    __shared__ int sCe, sCi;
    __shared__ unsigned sOfsE[NE + 48];    // element offsets n*RDIM, padded +48 for lookahead
    __shared__ unsigned sOfsI[NI + 48];

    const int tid = threadIdx.x;
    const int b = blockIdx.x;              // one block = one batch trajectory (independent)

    float v[NPT];
    int   acc[NPT];
    #pragma unroll
    for (int j = 0; j < NPT; ++j) { v[j] = 0.f; acc[j] = 0; }
    if (tid < RDIM) { sR1[tid] = 0.f; sR2[tid] = 0.f; sR3[tid] = 0.f; }
    __syncthreads();

    for (int t = 0; t < T_STEPS; ++t) {
        // ================= Phase E: expansion + LIF + spike (identical to R9) =================
        #pragma unroll
        for (int j = 0; j < NPT; ++j) {
            const int n = j * 256 + tid;        // j<32: e-neuron n; j>=32: i-neuron n-NE
            float I;
            if (j < 32) {
                const float4* Ua = (const float4*)(U_ee + (size_t)n * RDIM);
                const float4* Ub = (const float4*)(U_ie + (size_t)n * RDIM);
                float t1 = 0.f, t2 = 0.f;
                #pragma unroll
                for (int q = 0; q < 8; ++q) {
                    float4 ua = Ua[q], ub = Ub[q];
                    t1 = __fadd_rn(t1, __fmul_rn(sR1[4*q+0], ua.x));
                    t1 = __fadd_rn(t1, __fmul_rn(sR1[4*q+1], ua.y));
                    t1 = __fadd_rn(t1, __fmul_rn(sR1[4*q+2], ua.z));
                    t1 = __fadd_rn(t1, __fmul_rn(sR1[4*q+3], ua.w));
                    t2 = __fadd_rn(t2, __fmul_rn(sR3[4*q+0], ub.x));
                    t2 = __fadd_rn(t2, __fmul_rn(sR3[4*q+1], ub.y));
                    t2 = __fadd_rn(t2, __fmul_rn(sR3[4*q+2], ub.z));
                    t2 = __fadd_rn(t2, __fmul_rn(sR3[4*q+3], ub.w));
                }
                I = __fadd_rn(__fadd_rn(t1, t2),
                              ext[((size_t)b * T_STEPS + t) * NE + n]);
            } else {
                const float4* Uc = (const float4*)(U_ei + (size_t)(n - NE) * RDIM);
                float t1 = 0.f;
                #pragma unroll
                for (int q = 0; q < 8; ++q) {
                    float4 uc = Uc[q];
                    t1 = __fadd_rn(t1, __fmul_rn(sR2[4*q+0], uc.x));
                    t1 = __fadd_rn(t1, __fmul_rn(sR2[4*q+1], uc.y));
                    t1 = __fadd_rn(t1, __fmul_rn(sR2[4*q+2], uc.z));
                    t1 = __fadd_rn(t1, __fmul_rn(sR2[4*q+3], uc.w));
                }
                I = t1;
            }
            v[j] = __fadd_rn(__fmul_rn(v[j], DECAYF), I);   // v*decay then +I (numpy order)
            const bool sp = (v[j] >= 1.0f);
            acc[j] += sp ? 1 : 0;
            if (sp) v[j] = 0.f;
            const unsigned long long bal = __ballot(sp);
            const int w = tid >> 6;
            if ((tid & 63) == 0)  mw[j*8 + 2*w]     = (unsigned)bal;
            if ((tid & 63) == 32) mw[j*8 + 2*w + 1] = (unsigned)(bal >> 32);
        }
        if (t == T_STEPS - 1) break;
        __syncthreads();

        // ===== (a) wave-parallel order-preserving compaction (256 thr / 320 words) =====
        for (int w = tid; w < NW; w += 256) pc[w] = (unsigned)__popc(mw[w]);
        __syncthreads();
        for (int d = 1; d < 256; d <<= 1) {    // segmented inclusive scan: e [0,256), i [256,320)
            unsigned a0 = 0u, a1 = 0u;
            if (tid >= d) a0 = pc[tid - d];                     // e-segment element tid
            if (tid < 64 && tid >= d) a1 = pc[256 + tid - d];   // i-segment element tid
            __syncthreads();
            if (tid >= d) pc[tid] += a0;
            if (tid < 64 && tid >= d) pc[256 + tid] += a1;
            __syncthreads();
        }
        if (tid == 0)  sCe = (int)pc[255];
        if (tid == 64) sCi = (int)pc[319];
        for (int w = tid; w < NW; w += 256) {
            unsigned m = mw[w];
            int off = (int)pc[w] - __popc(m);
            if (w < 256) {
                const unsigned nb = (unsigned)w * 32u;
                while (m) { const int bit = __ffs(m) - 1; m &= m - 1;
                    sOfsE[off++] = (nb + (unsigned)bit) * (unsigned)RDIM; }
            } else {
                const unsigned nb = (unsigned)(w - 256) * 32u;
                while (m) { const int bit = __ffs(m) - 1; m &= m - 1;
                    sOfsI[off++] = (nb + (unsigned)bit) * (unsigned)RDIM; }
            }
        }
        __syncthreads();
        if (tid < 48)                      sOfsE[sCe + tid] = 0u;
        else if (tid >= 64 && tid < 112)   sOfsI[sCi + (tid - 64)] = 0u;
        __syncthreads();

        // ===== (b) serial chains, 3-deep x16 pipeline (ascending order preserved) =====
        if (tid < 96) {
            const int tb = tid >> 5;                // 0: V_ee, 1: V_ei (e-list), 2: V_ie (i-list)
            const int r = tid & 31;
            const float* __restrict__ V = ((tb == 0) ? V_ee : (tb == 1) ? V_ei : V_ie) + r;
            const unsigned* __restrict__ ofs = (tb == 2) ? sOfsI : sOfsE;
            const int cnt = (tb == 2) ? sCi : sCe;
            const int full = cnt >> 4;
            const int tail = cnt & 15;
            float a = 0.f;
            float xa[16], xb[16], xc[16];
            #pragma unroll
            for (int u = 0; u < 16; ++u) xa[u] = V[ofs[u]];
            #pragma unroll
            for (int u = 0; u < 16; ++u) xb[u] = V[ofs[16 + u]];
            #pragma unroll
            for (int u = 0; u < 16; ++u) xc[u] = V[ofs[32 + u]];
            int g = 0;
            for (; g + 3 <= full; g += 3) {
                #pragma unroll
                for (int u = 0; u < 16; ++u) a = __fadd_rn(a, xa[u]);
                #pragma unroll
                for (int u = 0; u < 16; ++u) xa[u] = V[ofs[(g + 3) * 16 + u]];
                #pragma unroll
                for (int u = 0; u < 16; ++u) a = __fadd_rn(a, xb[u]);
                #pragma unroll
                for (int u = 0; u < 16; ++u) xb[u] = V[ofs[(g + 4) * 16 + u]];
                #pragma unroll
                for (int u = 0; u < 16; ++u) a = __fadd_rn(a, xc[u]);
                #pragma unroll
                for (int u = 0; u < 16; ++u) xc[u] = V[ofs[(g + 5) * 16 + u]];
            }
            const int rem = full - g;               // 0, 1, or 2
            if (rem == 0) {
                #pragma unroll
                for (int u = 0; u < 16; ++u) if (u < tail) a = __fadd_rn(a, xa[u]);
            } else if (rem == 1) {
                #pragma unroll
                for (int u = 0; u < 16; ++u) a = __fadd_rn(a, xa[u]);
                #pragma unroll
                for (int u = 0; u < 16; ++u) if (u < tail) a = __fadd_rn(a, xb[u]);
            } else {
                #pragma unroll
                for (int u = 0; u < 16; ++u) a = __fadd_rn(a, xa[u]);
                #pragma unroll
                for (int u = 0; u < 16; ++u) a = __fadd_rn(a, xb[u]);
                #pragma unroll
                for (int u = 0; u < 16; ++u) if (u < tail) a = __fadd_rn(a, xc[u]);
            }
            ((tb == 0) ? sR1 : (tb == 1) ? sR2 : sR3)[r] = a;
        }
        __syncthreads();
    }

    // ================= output: spike counts [B][Ne+Ni] =================
    #pragma unroll
    for (int j = 0; j < NPT; ++j) {
        const int n = j * 256 + tid;
        out[(size_t)b * NTOT + n] = (float)acc[j];
    }
}

extern "C" void kernel_launch(void* const* d_in, const int* in_sizes, int n_in,
                              void* d_out, int out_size, void* d_ws, size_t ws_size,
                              hipStream_t stream) {
    (void)in_sizes; (void)n_in; (void)d_ws; (void)ws_size; (void)out_size;
    const float* ext  = (const float*)d_in[0];
    const float* U_ee = (const float*)d_in[1];
    const float* V_ee = (const float*)d_in[2];
    const float* U_ei = (const float*)d_in[3];
    const float* V_ei = (const float*)d_in[4];
    const float* U_ie = (const float*)d_in[5];
    const float* V_ie = (const float*)d_in[6];

    snn_fast<<<dim3(BTOT), dim3(256), 0, stream>>>(
        ext, U_ee, V_ee, U_ei, V_ei, U_ie, V_ie, (float*)d_out);
}

// Round 13
// 4187.119 us; speedup vs baseline: 9.7479x; 6.3065x over previous
//
#include <hip/hip_runtime.h>

// R13: 256 blocks (32 batches x 8 slices), 512 thr, U_ee slice in LDS,
// LLC parity-mask exchange + per-group counter sync, redundant serial chains.
// Arithmetic order byte-identical to R9/R12 (passed, absmax 0).

#define T_STEPS 128
#define NE 8192
#define NI 2048
#define NTOT 10240
#define RDIM 32
#define BATCHES 32
#define SLICES 8
#define SE 1024              // e-neurons per slice
#define SI 256               // i-neurons per slice
#define NT 512
#define NWB 320              // mask words per batch: e 256 + i 64
#define DECAYF 0.904837429523468017578125f   // f32(exp(f32(-0.1)))

__device__ unsigned g_masks[2][BATCHES][NWB];   // parity-double-buffered spike masks
__device__ unsigned g_cnt[BATCHES * 16];        // per-batch-group step counters

__global__ __launch_bounds__(NT, 1)
void snn_sliced(const float* __restrict__ ext,
                const float* __restrict__ U_ee, const float* __restrict__ V_ee,
                const float* __restrict__ U_ei, const float* __restrict__ V_ei,
                const float* __restrict__ U_ie, const float* __restrict__ V_ie,
                float* __restrict__ out)
{
    __shared__ __align__(16) float sUee[SE][RDIM];   // 128 KB, staged once
    __shared__ float sR1[RDIM], sR2[RDIM], sR3[RDIM];
    __shared__ unsigned mw[NWB], pc[NWB];
    __shared__ unsigned short sIdxE[NE + 48];        // ascending spike indices + pad
    __shared__ unsigned short sIdxI[NI + 48];
    __shared__ int sCe, sCi;

    const int tid = threadIdx.x;
    const int b = blockIdx.x / SLICES;
    const int s = blockIdx.x % SLICES;

    // ---- stage U_ee slice into LDS (once) ----
    {
        const float4* src = (const float4*)(U_ee + (size_t)s * SE * RDIM);
        float4* dst = (float4*)&sUee[0][0];
        for (int k = tid; k < SE * (RDIM / 4); k += NT) dst[k] = src[k];
    }
    if (tid < RDIM) { sR1[tid] = 0.f; sR2[tid] = 0.f; sR3[tid] = 0.f; }
    __syncthreads();

    float v0 = 0.f, v1 = 0.f, vi = 0.f;
    int a0 = 0, a1 = 0, ai = 0;
    unsigned* cnt = &g_cnt[b * 16];
    const float* Uie_s = U_ie + (size_t)s * SE * RDIM;
    const float* Uei_s = U_ei + (size_t)s * SI * RDIM;

    for (int t = 0; t < T_STEPS; ++t) {
        const int par = t & 1;
        unsigned* gm = &g_masks[par][b][0];

        // ============ Phase E: expansion + LIF (order identical to R9/R12) ============
        bool sp0, sp1, spi = false;
        {
            const float* extb = ext + ((size_t)b * T_STEPS + t) * NE + (size_t)s * SE;
            // e-neuron j=0: local le = tid
            {
                const float4* Ua = (const float4*)&sUee[tid][0];
                const float4* Ub = (const float4*)(Uie_s + (size_t)tid * RDIM);
                float t1 = 0.f, t2 = 0.f;
                #pragma unroll
                for (int q = 0; q < 8; ++q) {
                    const float4 ua = Ua[q], ub = Ub[q];
                    t1 = __fadd_rn(t1, __fmul_rn(sR1[4*q+0], ua.x));
                    t1 = __fadd_rn(t1, __fmul_rn(sR1[4*q+1], ua.y));
                    t1 = __fadd_rn(t1, __fmul_rn(sR1[4*q+2], ua.z));
                    t1 = __fadd_rn(t1, __fmul_rn(sR1[4*q+3], ua.w));
                    t2 = __fadd_rn(t2, __fmul_rn(sR3[4*q+0], ub.x));
                    t2 = __fadd_rn(t2, __fmul_rn(sR3[4*q+1], ub.y));
                    t2 = __fadd_rn(t2, __fmul_rn(sR3[4*q+2], ub.z));
                    t2 = __fadd_rn(t2, __fmul_rn(sR3[4*q+3], ub.w));
                }
                const float I = __fadd_rn(__fadd_rn(t1, t2), extb[tid]);
                v0 = __fadd_rn(__fmul_rn(v0, DECAYF), I);
                sp0 = (v0 >= 1.0f); a0 += sp0 ? 1 : 0; if (sp0) v0 = 0.f;
            }
            // e-neuron j=1: local le = 512 + tid
            {
                const float4* Ua = (const float4*)&sUee[512 + tid][0];
                const float4* Ub = (const float4*)(Uie_s + (size_t)(512 + tid) * RDIM);
                float t1 = 0.f, t2 = 0.f;
                #pragma unroll
                for (int q = 0; q < 8; ++q) {
                    const float4 ua = Ua[q], ub = Ub[q];
                    t1 = __fadd_rn(t1, __fmul_rn(sR1[4*q+0], ua.x));
                    t1 = __fadd_rn(t1, __fmul_rn(sR1[4*q+1], ua.y));
                    t1 = __fadd_rn(t1, __fmul_rn(sR1[4*q+2], ua.z));
                    t1 = __fadd_rn(t1, __fmul_rn(sR1[4*q+3], ua.w));
                    t2 = __fadd_rn(t2, __fmul_rn(sR3[4*q+0], ub.x));
                    t2 = __fadd_rn(t2, __fmul_rn(sR3[4*q+1], ub.y));
                    t2 = __fadd_rn(t2, __fmul_rn(sR3[4*q+2], ub.z));
                    t2 = __fadd_rn(t2, __fmul_rn(sR3[4*q+3], ub.w));
                }
                const float I = __fadd_rn(__fadd_rn(t1, t2), extb[512 + tid]);
                v1 = __fadd_rn(__fmul_rn(v1, DECAYF), I);
                sp1 = (v1 >= 1.0f); a1 += sp1 ? 1 : 0; if (sp1) v1 = 0.f;
            }
            // i-neuron (tid<256): local li = tid
            if (tid < 256) {
                const float4* Uc = (const float4*)(Uei_s + (size_t)tid * RDIM);
                float t1 = 0.f;
                #pragma unroll
                for (int q = 0; q < 8; ++q) {
                    const float4 uc = Uc[q];
                    t1 = __fadd_rn(t1, __fmul_rn(sR2[4*q+0], uc.x));
                    t1 = __fadd_rn(t1, __fmul_rn(sR2[4*q+1], uc.y));
                    t1 = __fadd_rn(t1, __fmul_rn(sR2[4*q+2], uc.z));
                    t1 = __fadd_rn(t1, __fmul_rn(sR2[4*q+3], uc.w));
                }
                vi = __fadd_rn(__fmul_rn(vi, DECAYF), t1);
                spi = (vi >= 1.0f); ai += spi ? 1 : 0; if (spi) vi = 0.f;
            }
        }
        if (t == T_STEPS - 1) break;

        // ============ publish slice masks to LLC (parity buffer) ============
        {
            const int wv = tid >> 6;
            const unsigned long long bal0 = __ballot(sp0);
            if ((tid & 63) == 0)
                __hip_atomic_store(&gm[s*32 + wv*2],     (unsigned)bal0,        __ATOMIC_RELAXED, __HIP_MEMORY_SCOPE_AGENT);
            if ((tid & 63) == 32)
                __hip_atomic_store(&gm[s*32 + wv*2 + 1], (unsigned)(bal0 >> 32), __ATOMIC_RELAXED, __HIP_MEMORY_SCOPE_AGENT);
            const unsigned long long bal1 = __ballot(sp1);
            if ((tid & 63) == 0)
                __hip_atomic_store(&gm[s*32 + 16 + wv*2],     (unsigned)bal1,        __ATOMIC_RELAXED, __HIP_MEMORY_SCOPE_AGENT);
            if ((tid & 63) == 32)
                __hip_atomic_store(&gm[s*32 + 16 + wv*2 + 1], (unsigned)(bal1 >> 32), __ATOMIC_RELAXED, __HIP_MEMORY_SCOPE_AGENT);
            if (tid < 256) {
                const unsigned long long bi2 = __ballot(spi);
                if ((tid & 63) == 0)
                    __hip_atomic_store(&gm[256 + s*8 + wv*2],     (unsigned)bi2,        __ATOMIC_RELAXED, __HIP_MEMORY_SCOPE_AGENT);
                if ((tid & 63) == 32)
                    __hip_atomic_store(&gm[256 + s*8 + wv*2 + 1], (unsigned)(bi2 >> 32), __ATOMIC_RELAXED, __HIP_MEMORY_SCOPE_AGENT);
            }
        }
        asm volatile("s_waitcnt vmcnt(0)" ::: "memory");
        __syncthreads();
        // ============ per-group counter sync ============
        if (tid == 0) {
            __hip_atomic_fetch_add(cnt, 1u, __ATOMIC_RELAXED, __HIP_MEMORY_SCOPE_AGENT);
            const unsigned target = (unsigned)SLICES * (unsigned)(t + 1);
            while (__hip_atomic_load(cnt, __ATOMIC_RELAXED, __HIP_MEMORY_SCOPE_AGENT) < target)
                __builtin_amdgcn_s_sleep(2);
        }
        __syncthreads();
        // ============ read whole-batch masks ============
        if (tid < NWB)
            mw[tid] = __hip_atomic_load(&gm[tid], __ATOMIC_RELAXED, __HIP_MEMORY_SCOPE_AGENT);
        __syncthreads();
        // ============ compaction: popc + segmented scan + expand (1:1 tid<->word) ============
        if (tid < NWB) pc[tid] = (unsigned)__popc(mw[tid]);
        __syncthreads();
        for (int d = 1; d < 256; d <<= 1) {
            unsigned add = 0u; bool act = false;
            if (tid < 256)            { if (tid >= d)         { add = pc[tid - d]; act = true; } }
            else if (tid < NWB)       { if (tid - 256 >= d)   { add = pc[tid - d]; act = true; } }
            __syncthreads();
            if (act) pc[tid] += add;
            __syncthreads();
        }
        if (tid == 0)  sCe = (int)pc[255];
        if (tid == 64) sCi = (int)pc[319];
        __syncthreads();
        if (tid < NWB) {
            unsigned m = mw[tid];
            int off = (int)pc[tid] - __popc(m);
            if (tid < 256) {
                const unsigned nb = (unsigned)tid * 32u;
                while (m) { const int bit = __ffs(m) - 1; m &= m - 1;
                    sIdxE[off++] = (unsigned short)(nb + (unsigned)bit); }
            } else {
                const unsigned nb = (unsigned)(tid - 256) * 32u;
                while (m) { const int bit = __ffs(m) - 1; m &= m - 1;
                    sIdxI[off++] = (unsigned short)(nb + (unsigned)bit); }
            }
        }
        if (tid >= 320 && tid < 368)      sIdxE[sCe + (tid - 320)] = 0;
        else if (tid >= 384 && tid < 432) sIdxI[sCi + (tid - 384)] = 0;
        __syncthreads();
        // ============ serial chains, 3-deep x16 pipeline (ascending, redundant/block) ============
        if (tid < 96) {
            const int tb = tid >> 5;            // 0: V_ee(e-list), 1: V_ei(e-list), 2: V_ie(i-list)
            const int r = tid & 31;
            const float* __restrict__ V = ((tb == 0) ? V_ee : (tb == 1) ? V_ei : V_ie) + r;
            const unsigned short* __restrict__ ip = (tb == 2) ? sIdxI : sIdxE;
            const int cnt2 = (tb == 2) ? sCi : sCe;
            const int full = cnt2 >> 4;
            const int tail = cnt2 & 15;
            float a = 0.f;
            float xa[16], xb[16], xc[16];
            #pragma unroll
            for (int u = 0; u < 16; ++u) xa[u] = V[(unsigned)ip[u] * 32u];
            #pragma unroll
            for (int u = 0; u < 16; ++u) xb[u] = V[(unsigned)ip[16 + u] * 32u];
            #pragma unroll
            for (int u = 0; u < 16; ++u) xc[u] = V[(unsigned)ip[32 + u] * 32u];
            int g = 0;
            for (; g + 3 <= full; g += 3) {
                #pragma unroll
                for (int u = 0; u < 16; ++u) a = __fadd_rn(a, xa[u]);
                #pragma unroll
                for (int u = 0; u < 16; ++u) xa[u] = V[(unsigned)ip[(g + 3) * 16 + u] * 32u];
                #pragma unroll
                for (int u = 0; u < 16; ++u) a = __fadd_rn(a, xb[u]);
                #pragma unroll
                for (int u = 0; u < 16; ++u) xb[u] = V[(unsigned)ip[(g + 4) * 16 + u] * 32u];
                #pragma unroll
                for (int u = 0; u < 16; ++u) a = __fadd_rn(a, xc[u]);
                #pragma unroll
                for (int u = 0; u < 16; ++u) xc[u] = V[(unsigned)ip[(g + 5) * 16 + u] * 32u];
            }
            const int rem = full - g;           // 0, 1, or 2
            if (rem == 0) {
                #pragma unroll
                for (int u = 0; u < 16; ++u) if (u < tail) a = __fadd_rn(a, xa[u]);
            } else if (rem == 1) {
                #pragma unroll
                for (int u = 0; u < 16; ++u) a = __fadd_rn(a, xa[u]);
                #pragma unroll
                for (int u = 0; u < 16; ++u) if (u < tail) a = __fadd_rn(a, xb[u]);
            } else {
                #pragma unroll
                for (int u = 0; u < 16; ++u) a = __fadd_rn(a, xa[u]);
                #pragma unroll
                for (int u = 0; u < 16; ++u) a = __fadd_rn(a, xb[u]);
                #pragma unroll
                for (int u = 0; u < 16; ++u) if (u < tail) a = __fadd_rn(a, xc[u]);
            }
            ((tb == 0) ? sR1 : (tb == 1) ? sR2 : sR3)[r] = a;
        }
        __syncthreads();
    }

    // ============ outputs: spike counts [B][Ne+Ni] ============
    {
        float* ob = out + (size_t)b * NTOT;
        ob[(size_t)s * SE + tid]       = (float)a0;
        ob[(size_t)s * SE + 512 + tid] = (float)a1;
        if (tid < 256) ob[NE + (size_t)s * SI + tid] = (float)ai;
    }
}

extern "C" void kernel_launch(void* const* d_in, const int* in_sizes, int n_in,
                              void* d_out, int out_size, void* d_ws, size_t ws_size,
                              hipStream_t stream) {
    (void)in_sizes; (void)n_in; (void)d_ws; (void)ws_size; (void)out_size;
    const float* ext  = (const float*)d_in[0];
    const float* U_ee = (const float*)d_in[1];
    const float* V_ee = (const float*)d_in[2];
    const float* U_ei = (const float*)d_in[3];
    const float* V_ei = (const float*)d_in[4];
    const float* U_ie = (const float*)d_in[5];
    const float* V_ie = (const float*)d_in[6];

    void* p = nullptr;
    hipGetSymbolAddress(&p, HIP_SYMBOL(g_cnt));
    hipMemsetAsync(p, 0, sizeof(unsigned) * BATCHES * 16, stream);

    snn_sliced<<<dim3(BATCHES * SLICES), dim3(NT), 0, stream>>>(
        ext, U_ee, V_ee, U_ei, V_ei, U_ie, V_ie, (float*)d_out);
}